// Round 6
// baseline (1166.755 us; speedup 1.0000x reference)
//
#include <hip/hip_runtime.h>
#include <stdint.h>

#define NTOK 65536
#define KDIM 1280

typedef __attribute__((ext_vector_type(8))) short short8;
typedef __attribute__((ext_vector_type(4))) float floatx4;

__device__ __forceinline__ unsigned short f2bf(float f) {
  union { float f; unsigned int u; } v; v.f = f;
  unsigned int r = v.u + 0x7FFFu + ((v.u >> 16) & 1u);  // RNE
  return (unsigned short)(r >> 16);
}

// packed f32x2 -> bf16x2 (RNE), single HW instruction
__device__ __forceinline__ unsigned cvtpk(float lo, float hi) {
  unsigned r;
  asm("v_cvt_pk_bf16_f32 %0, %1, %2" : "=v"(r) : "v"(lo), "v"(hi));
  return r;
}

// ---------------- merged pack kernel (W1, W2, Wg) ----------------
// 380,928 threads = 1488 blocks x 256 exactly.

__global__ __launch_bounds__(256)
void pack_all_kernel(const float* __restrict__ W1, const float* __restrict__ W2,
                     const float* __restrict__ Wg,
                     unsigned short* __restrict__ W1t, unsigned short* __restrict__ W2t,
                     unsigned short* __restrict__ WgTb) {
  int t = blockIdx.x * 256 + threadIdx.x;
  if (t < 327680) {  // W1 [E][1280][256] -> W1t [n=e*256+h][k]
    int n = t / 160, kg = t - n * 160;
    int e = n >> 8, h = n & 255;
    int k = kg * 8;
    const float* src = W1 + ((size_t)e * 1280 + k) * 256 + h;
    uint4 o;
    o.x = (unsigned)f2bf(src[0])       | ((unsigned)f2bf(src[256])     << 16);
    o.y = (unsigned)f2bf(src[2 * 256]) | ((unsigned)f2bf(src[3 * 256]) << 16);
    o.z = (unsigned)f2bf(src[4 * 256]) | ((unsigned)f2bf(src[5 * 256]) << 16);
    o.w = (unsigned)f2bf(src[6 * 256]) | ((unsigned)f2bf(src[7 * 256]) << 16);
    *(uint4*)(W1t + (size_t)n * 1280 + k) = o;
  } else if (t < 360448) {  // W2 [E][256][128] -> W2t [e*128+n][k]
    int t2 = t - 327680;
    int ng = t2 >> 5, kg = t2 & 31;
    int e = ng >> 7, n = ng & 127;
    int k = kg * 8;
    const float* src = W2 + (size_t)e * 32768 + (size_t)k * 128 + n;
    uint4 o;
    o.x = (unsigned)f2bf(src[0])       | ((unsigned)f2bf(src[128])     << 16);
    o.y = (unsigned)f2bf(src[2 * 128]) | ((unsigned)f2bf(src[3 * 128]) << 16);
    o.z = (unsigned)f2bf(src[4 * 128]) | ((unsigned)f2bf(src[5 * 128]) << 16);
    o.w = (unsigned)f2bf(src[6 * 128]) | ((unsigned)f2bf(src[7 * 128]) << 16);
    *(uint4*)(W2t + (size_t)ng * 256 + k) = o;
  } else {  // Wg [1280][8] -> WgTb [16][1280] (rows 8..15 zero)
    int t3 = t - 360448;
    int e = t3 / 1280, k = t3 - e * 1280;
    WgTb[t3] = (e < 8) ? f2bf(Wg[(size_t)k * 8 + e]) : (unsigned short)0;
  }
}

// ---------------- fused expert MLP (+gate on e==0 blocks) ----------------
// Flatmm shape: W (A-operand) loaded DIRECT global->reg (per-wave private, no
// LDS staging, no barrier dependency -> compiler software-pipelines via vmcnt);
// x (B-operand, shared by all 4 waves) in LDS, double-buffered, prefetched one
// BK-iteration ahead -> ONE barrier per K-iter with an empty drain.
// Phase 2 K-loop is barrier-free (W2 direct, h1L resident).
// LDS 49152 B, __launch_bounds__(256,3) -> 3 blocks/CU.
// Remap: XCD c = wg&7 owns tiles c*128..c*128+127; within XCD, 16-tile chunks
// with expert varying every 16 blocks (x L2-reuse in-chunk; W L3-resident).

__global__ __launch_bounds__(256, 3)
void expert_fused_kernel(const float* __restrict__ xf,
                         const unsigned short* __restrict__ W1t,
                         const float* __restrict__ b1,
                         const unsigned short* __restrict__ W2t,
                         const float* __restrict__ b2,
                         const float* __restrict__ W3,
                         const float* __restrict__ b3,
                         const unsigned short* __restrict__ WgTb,
                         const float* __restrict__ bg,
                         float* __restrict__ outG,
                         float* __restrict__ eo) {
  __shared__ __align__(16) unsigned short smem[24576];  // 49152 bytes
  // Xs: double buffer, each buffer = two 32-k slabs: [buf][slab][64][32]
  //   buf b at b*4096 shorts; slab s at s*2048 shorts within buf.
  unsigned short* Xs  = smem;            // 8192 shorts (16KB)
  unsigned short* h1L = smem + 8192;     // [64][256] swizzled, 16384 shorts (32KB)

  const int tid = threadIdx.x;
  const int wv = tid >> 6;
  const int lane = tid & 63;

  // XCD-grouped remap (bijective over 8192 blocks): c=XCD, 16-tile chunks,
  // expert varies every 16 blocks within a 128-block chunk.
  const int wg = blockIdx.x + (blockIdx.y << 3);  // dispatch-linear, x fastest
  const int c  = wg & 7;                          // XCD (round-robin heuristic)
  const int w  = wg >> 3;                         // per-XCD sequence 0..1023
  const int chunk = w >> 7;                       // 8 chunks of 128 blocks
  const int w7 = w & 127;
  const int e  = w7 >> 4;                         // expert (changes every 16)
  const int m0 = ((c << 7) + (chunk << 4) + (w7 & 15)) << 6;  // token tile base
  const bool gate_blk = (e == 0);

  const unsigned short* W1te = W1t + (size_t)e * 256 * 1280;
  const unsigned short* W2te = W2t + (size_t)e * 128 * 256;

  const int lr = lane >> 2;                                    // staging row-in-16
  const int ksw = ((lane & 3) ^ ((lane >> 3) & 3)) * 8;        // swizzled src k-offset
  const int fr = lane & 15;
  const int fkS = (((lane >> 4) ^ ((lane >> 1) & 3)) & 3) * 8; // swizzled frag slot
  const int fkL = (lane >> 4) * 8;                             // logical frag k-offset
  const int rq = (lane >> 4) * 4;

  const float* gxf = xf + (size_t)(m0 + wv * 16 + lr) * 1280 + ksw;
  const int xslot = (wv * 16 + lr) * 32 + (lane & 3) * 8;      // LDS write slot
  // direct-global fragment bases (logical k, no swizzle)
  const unsigned short* gw1 = W1te + (size_t)(wv * 64 + fr) * 1280 + fkL;
  const unsigned short* gwg = WgTb + (size_t)fr * 1280 + fkL;

  // ---- phase 1: h1^T tile (256 hidden x 64 tokens), K=1280, BK=64 ----
  floatx4 acc1[4][4] = {};
  floatx4 accg = {0.f, 0.f, 0.f, 0.f};

  // prologue: stage x slab-pair 0 into buffer 0
  {
    float4 a0 = *(const float4*)(gxf);
    float4 a1 = *(const float4*)(gxf + 4);
    float4 b0 = *(const float4*)(gxf + 32);
    float4 b1v = *(const float4*)(gxf + 36);
    uint4 pa, pb;
    pa.x = cvtpk(a0.x, a0.y); pa.y = cvtpk(a0.z, a0.w);
    pa.z = cvtpk(a1.x, a1.y); pa.w = cvtpk(a1.z, a1.w);
    pb.x = cvtpk(b0.x, b0.y); pb.y = cvtpk(b0.z, b0.w);
    pb.z = cvtpk(b1v.x, b1v.y); pb.w = cvtpk(b1v.z, b1v.w);
    *(uint4*)&Xs[xslot] = pa;
    *(uint4*)&Xs[2048 + xslot] = pb;
  }
  __syncthreads();

  for (int t = 0; t < 20; ++t) {
    const int k0 = t * 64;
    const int cur = (t & 1) << 12;   // *4096 shorts
    // prefetch x slab-pair t+1 (consumed just before the tail barrier)
    float4 na0, na1, nb0, nb1;
    if (t < 19) {
      na0 = *(const float4*)(gxf + k0 + 64);
      na1 = *(const float4*)(gxf + k0 + 68);
      nb0 = *(const float4*)(gxf + k0 + 96);
      nb1 = *(const float4*)(gxf + k0 + 100);
    }
#pragma unroll
    for (int s = 0; s < 2; ++s) {  // slab A (k0) / slab B (k0+32)
      const int kk = k0 + s * 32;
      const int xbase = cur + (s << 11);
      short8 bfv[4];
#pragma unroll
      for (int j = 0; j < 4; j++)
        bfv[j] = *(const short8*)&Xs[xbase + (j * 16 + fr) * 32 + fkS];
#pragma unroll
      for (int i = 0; i < 4; i++) {
        short8 af = *(const short8*)(gw1 + (size_t)(i * 16) * 1280 + kk);
#pragma unroll
        for (int j = 0; j < 4; j++)
          acc1[i][j] = __builtin_amdgcn_mfma_f32_16x16x32_bf16(af, bfv[j], acc1[i][j], 0, 0, 0);
      }
      if (gate_blk) {
        short8 ag = *(const short8*)(gwg + kk);
        short8 bgf = *(const short8*)&Xs[xbase + (wv * 16 + fr) * 32 + fkS];
        accg = __builtin_amdgcn_mfma_f32_16x16x32_bf16(ag, bgf, accg, 0, 0, 0);
      }
    }
    if (t < 19) {
      const int nxt = cur ^ 4096;
      uint4 pa, pb;
      pa.x = cvtpk(na0.x, na0.y); pa.y = cvtpk(na0.z, na0.w);
      pa.z = cvtpk(na1.x, na1.y); pa.w = cvtpk(na1.z, na1.w);
      pb.x = cvtpk(nb0.x, nb0.y); pb.y = cvtpk(nb0.z, nb0.w);
      pb.z = cvtpk(nb1.x, nb1.y); pb.w = cvtpk(nb1.z, nb1.w);
      *(uint4*)&Xs[nxt + xslot] = pa;
      *(uint4*)&Xs[nxt + 2048 + xslot] = pb;
    }
    __syncthreads();  // next buffer visible; drain is empty (x prefetched, af consumed)
  }

  // ---- gate epilogue (e==0 blocks): softmax over 8 experts, write outG ----
  // accg layout: col(lane&15)=token-in-group(wv), row((lane>>4)*4+r)=expert.
  if (gate_blk) {
    const int g = lane >> 4;
    float bg0 = 0.f, bg1 = 0.f, bg2 = 0.f, bg3 = 0.f;
    if (g < 2) {
      float4 t = *(const float4*)(bg + g * 4);
      bg0 = t.x; bg1 = t.y; bg2 = t.z; bg3 = t.w;
    }
    float v0 = accg[0] + bg0, v1 = accg[1] + bg1, v2 = accg[2] + bg2, v3 = accg[3] + bg3;
    float mx = fmaxf(fmaxf(v0, v1), fmaxf(v2, v3));
    mx = fmaxf(mx, __shfl_xor(mx, 16));  // pairs g0<->g1 (g2/g3 junk stays separate)
    float e0 = __expf(v0 - mx), e1 = __expf(v1 - mx), e2 = __expf(v2 - mx), e3 = __expf(v3 - mx);
    float s = e0 + e1 + e2 + e3;
    s += __shfl_xor(s, 16);
    float inv = 1.f / s;
    if (g < 2) {
      float4 o; o.x = e0 * inv; o.y = e1 * inv; o.z = e2 * inv; o.w = e3 * inv;
      *(float4*)&outG[(size_t)(m0 + wv * 16 + fr) * 8 + g * 4] = o;
    }
  }

  // ---- epilogue 1: relu(+b1), bf16, transpose into swizzled h1L[token][k] ----
#pragma unroll
  for (int i = 0; i < 4; i++) {
    const int rowb = wv * 64 + i * 16 + rq;  // hidden k-index base (4 consecutive)
    const float4 bb = *(const float4*)(b1 + e * 256 + rowb);  // L2-hot
#pragma unroll
    for (int j = 0; j < 4; j++) {
      float v0 = acc1[i][j][0] + bb.x; v0 = v0 > 0.f ? v0 : 0.f;
      float v1 = acc1[i][j][1] + bb.y; v1 = v1 > 0.f ? v1 : 0.f;
      float v2 = acc1[i][j][2] + bb.z; v2 = v2 > 0.f ? v2 : 0.f;
      float v3 = acc1[i][j][3] + bb.w; v3 = v3 > 0.f ? v3 : 0.f;
      uint2 pk;
      pk.x = (unsigned)f2bf(v0) | ((unsigned)f2bf(v1) << 16);
      pk.y = (unsigned)f2bf(v2) | ((unsigned)f2bf(v3) << 16);
      const int row = j * 16 + fr;  // token row
      *(uint2*)((char*)h1L + ((row * 512 + rowb * 2) ^ ((row & 7) << 4))) = pk;
    }
  }
  __syncthreads();

  // ---- phase 2: h2 tile (128 h2 x 64 tokens), K=256 -- barrier-free K-loop ----
  floatx4 acc2[2][4] = {};
  const unsigned short* gw2 = W2te + (size_t)(wv * 32 + fr) * 256 + fkL;
#pragma unroll
  for (int k0 = 0; k0 < 256; k0 += 32) {
    short8 b2v[4];
#pragma unroll
    for (int j = 0; j < 4; j++) {
      const int row = j * 16 + fr;
      b2v[j] = *(const short8*)((const char*)h1L +
               ((row * 512 + (k0 + fkL) * 2) ^ ((row & 7) << 4)));
    }
#pragma unroll
    for (int i = 0; i < 2; i++) {
      short8 a2 = *(const short8*)(gw2 + (size_t)(i * 16) * 256 + k0);
#pragma unroll
      for (int j = 0; j < 4; j++)
        acc2[i][j] = __builtin_amdgcn_mfma_f32_16x16x32_bf16(a2, b2v[j], acc2[i][j], 0, 0, 0);
    }
  }

  // ---- phase 3: expert_out = relu(h2+b2) . W3 ----
  float psum[4] = {0.f, 0.f, 0.f, 0.f};
#pragma unroll
  for (int i = 0; i < 2; i++) {
    const int rowb = wv * 32 + i * 16 + rq;  // h2 index base
    const float4 bb = *(const float4*)(b2 + e * 128 + rowb);
    const float4 ww = *(const float4*)(W3 + e * 128 + rowb);
    const float bba[4] = {bb.x, bb.y, bb.z, bb.w};
    const float wwa[4] = {ww.x, ww.y, ww.z, ww.w};
#pragma unroll
    for (int j = 0; j < 4; j++)
#pragma unroll
      for (int r = 0; r < 4; r++) {
        float v = acc2[i][j][r] + bba[r];
        v = v > 0.f ? v : 0.f;
        psum[j] += v * wwa[r];
      }
  }
#pragma unroll
  for (int j = 0; j < 4; j++) {
    float v = psum[j];
    v += __shfl_xor(v, 16);
    v += __shfl_xor(v, 32);
    psum[j] = v;
  }
  float* exS = (float*)Xs;  // Xs dead since end of phase 1
  if (lane < 16) {
#pragma unroll
    for (int j = 0; j < 4; j++) exS[wv * 64 + j * 16 + lane] = psum[j];
  }
  __syncthreads();
  if (tid < 64) {
    float tot = exS[tid] + exS[64 + tid] + exS[128 + tid] + exS[192 + tid];
    eo[(size_t)(m0 + tid) * 8 + e] = tot + b3[e];
  }
}

// ---------------- combine: predictions = sum(gate * eo) ----------------

__global__ __launch_bounds__(256)
void combine_kernel(const float* __restrict__ outG, const float* __restrict__ eo,
                    float* __restrict__ outP) {
  int t = blockIdx.x * 256 + threadIdx.x;
  const float4* g4 = (const float4*)(outG + (size_t)t * 8);
  const float4* e4 = (const float4*)(eo + (size_t)t * 8);
  float4 ga = g4[0], gb = g4[1], ea = e4[0], eb = e4[1];
  outP[t] = ga.x * ea.x + ga.y * ea.y + ga.z * ea.z + ga.w * ea.w +
            gb.x * eb.x + gb.y * eb.y + gb.z * eb.z + gb.w * eb.w;
}

// ---------------- launch ----------------

extern "C" void kernel_launch(void* const* d_in, const int* in_sizes, int n_in,
                              void* d_out, int out_size, void* d_ws, size_t ws_size,
                              hipStream_t stream) {
  const float* x  = (const float*)d_in[0];
  const float* W1 = (const float*)d_in[1];
  const float* b1 = (const float*)d_in[2];
  const float* W2 = (const float*)d_in[3];
  const float* b2 = (const float*)d_in[4];
  const float* W3 = (const float*)d_in[5];
  const float* b3 = (const float*)d_in[6];
  const float* Wg = (const float*)d_in[7];
  const float* bg = (const float*)d_in[8];
  float* outP = (float*)d_out;   // predictions [B] f32
  float* outG = outP + NTOK;     // gate [B][8] f32

  char* ws = (char*)d_ws;
  unsigned short* W1t  = (unsigned short*)ws;               //  5,242,880
  unsigned short* W2t  = (unsigned short*)(ws + 5242880ll); //    524,288
  unsigned short* WgTb = (unsigned short*)(ws + 5767168ll); //     40,960
  float*          eo   = (float*)(ws + 5808128ll);          //  2,097,152  (tot ~7.9MB)

  pack_all_kernel<<<1488, 256, 0, stream>>>(W1, W2, Wg, W1t, W2t, WgTb);
  expert_fused_kernel<<<dim3(8, 1024), 256, 0, stream>>>(x, W1t, b1, W2t, b2, W3, b3,
                                                         WgTb, bg, outG, eo);
  combine_kernel<<<256, 256, 0, stream>>>(outG, eo, outP);
}

// Round 7
// 1030.415 us; speedup vs baseline: 1.1323x; 1.1323x over previous
//
#include <hip/hip_runtime.h>
#include <stdint.h>

#define NTOK 65536
#define KDIM 1280

typedef __attribute__((ext_vector_type(8))) short short8;
typedef __attribute__((ext_vector_type(4))) float floatx4;

__device__ __forceinline__ unsigned short f2bf(float f) {
  union { float f; unsigned int u; } v; v.f = f;
  unsigned int r = v.u + 0x7FFFu + ((v.u >> 16) & 1u);  // RNE
  return (unsigned short)(r >> 16);
}

// packed f32x2 -> bf16x2 (RNE), single HW instruction
__device__ __forceinline__ unsigned cvtpk(float lo, float hi) {
  unsigned r;
  asm("v_cvt_pk_bf16_f32 %0, %1, %2" : "=v"(r) : "v"(lo), "v"(hi));
  return r;
}

// async global->LDS, 16B per lane; lds base wave-uniform (HW adds lane*16)
#define GLDS16(gp, lp) \
  __builtin_amdgcn_global_load_lds((const __attribute__((address_space(1))) void*)(gp), \
                                   (__attribute__((address_space(3))) void*)(lp), 16, 0, 0)

// ---------------- merged pack kernel (W1, W2, Wg) ----------------
// 380,928 threads = 1488 blocks x 256 exactly.

__global__ __launch_bounds__(256)
void pack_all_kernel(const float* __restrict__ W1, const float* __restrict__ W2,
                     const float* __restrict__ Wg,
                     unsigned short* __restrict__ W1t, unsigned short* __restrict__ W2t,
                     unsigned short* __restrict__ WgTb) {
  int t = blockIdx.x * 256 + threadIdx.x;
  if (t < 327680) {  // W1 [E][1280][256] -> W1t [n=e*256+h][k]
    int n = t / 160, kg = t - n * 160;
    int e = n >> 8, h = n & 255;
    int k = kg * 8;
    const float* src = W1 + ((size_t)e * 1280 + k) * 256 + h;
    uint4 o;
    o.x = (unsigned)f2bf(src[0])       | ((unsigned)f2bf(src[256])     << 16);
    o.y = (unsigned)f2bf(src[2 * 256]) | ((unsigned)f2bf(src[3 * 256]) << 16);
    o.z = (unsigned)f2bf(src[4 * 256]) | ((unsigned)f2bf(src[5 * 256]) << 16);
    o.w = (unsigned)f2bf(src[6 * 256]) | ((unsigned)f2bf(src[7 * 256]) << 16);
    *(uint4*)(W1t + (size_t)n * 1280 + k) = o;
  } else if (t < 360448) {  // W2 [E][256][128] -> W2t [e*128+n][k]
    int t2 = t - 327680;
    int ng = t2 >> 5, kg = t2 & 31;
    int e = ng >> 7, n = ng & 127;
    int k = kg * 8;
    const float* src = W2 + (size_t)e * 32768 + (size_t)k * 128 + n;
    uint4 o;
    o.x = (unsigned)f2bf(src[0])       | ((unsigned)f2bf(src[128])     << 16);
    o.y = (unsigned)f2bf(src[2 * 128]) | ((unsigned)f2bf(src[3 * 128]) << 16);
    o.z = (unsigned)f2bf(src[4 * 128]) | ((unsigned)f2bf(src[5 * 128]) << 16);
    o.w = (unsigned)f2bf(src[6 * 128]) | ((unsigned)f2bf(src[7 * 128]) << 16);
    *(uint4*)(W2t + (size_t)ng * 256 + k) = o;
  } else {  // Wg [1280][8] -> WgTb [16][1280] (rows 8..15 zero)
    int t3 = t - 360448;
    int e = t3 / 1280, k = t3 - e * 1280;
    WgTb[t3] = (e < 8) ? f2bf(Wg[(size_t)k * 8 + e]) : (unsigned short)0;
  }
}

// ---------------- fused expert MLP (+gate on e==0 blocks) ----------------
// Counted-wait double-buffer (T3/T4 adapted):
//  - All staging via GLDS16 (async, r3-proven). Per iter: issue tile t+1's
//    loads right AFTER the barrier, compute tile t, and the vmcnt(0) wait for
//    t+1 happens at the NEXT iteration top -> one full compute phase of slack
//    (r3 drained just-issued loads at every __syncthreads = exposed latency).
//  - W staging is wave-private (each wave stages+consumes its own rows); only
//    x/Wg are cross-wave -> ONE raw s_barrier per iter, NO barriers in phase 2.
//  - x staged as f32 (GLDS16, pre-swizzled source) and converted to bf16 by
//    v_cvt_pk after ds_read -> cast_x kernel + xb workspace deleted.
// LDS 51200 B -> 3 blocks/CU with __launch_bounds__(256,3) (r2/r3: no spill).
// Layout (bytes): Ws dbuf 2x16K @0 | Xf dbuf 2x8K(f32) @32768 | WgS 2x1K @49152
//   h1L [64][256] bf16 @0 (aliases Ws, post phase 1)
//   W2 dbuf 2x8K @32768 (aliases Xf, phase 2) | exS 1K @32768 (phase 3)

__global__ __launch_bounds__(256, 3)
void expert_fused_kernel(const float* __restrict__ xf,
                         const unsigned short* __restrict__ W1t,
                         const float* __restrict__ b1,
                         const unsigned short* __restrict__ W2t,
                         const float* __restrict__ b2,
                         const float* __restrict__ W3,
                         const float* __restrict__ b3,
                         const unsigned short* __restrict__ WgTb,
                         const float* __restrict__ bg,
                         float* __restrict__ outG,
                         float* __restrict__ eo) {
  __shared__ __align__(16) unsigned short smem[25600];  // 51200 bytes
  unsigned short* Ws  = smem;                    // 2 bufs x [256][32] bf16
  char* XfB = (char*)smem + 32768;               // 2 bufs x [64][32] f32
  unsigned short* WgS = smem + 24576;            // byte 49152: 2 bufs x [16][32]
  unsigned short* h1L = smem;                    // aliases Ws (post phase 1)

  const int tid = threadIdx.x;
  const int wv = tid >> 6;
  const int lane = tid & 63;
  const int e = blockIdx.x;           // identity mapping (r3-proven, 706MB FETCH)
  const int m0 = blockIdx.y << 6;
  const bool gate_blk = (e == 0);
  const bool gate_stager = gate_blk && (wv == 0);

  const unsigned short* W1te = W1t + (size_t)e * 256 * 1280;
  const unsigned short* W2te = W2t + (size_t)e * 128 * 256;

  const int lr = lane >> 2;                                    // W-chunk row-in-16
  const int ksw = ((lane & 3) ^ ((lane >> 3) & 3)) * 8;        // W src k pre-swizzle
  const int fr = lane & 15;
  const int fkS = (((lane >> 4) ^ ((lane >> 1) & 3)) & 3) * 8; // W frag slot (swz)
  const int fkL = (lane >> 4) * 8;                             // logical frag k-off
  const int rq = (lane >> 4) * 4;

  // W1 staging: wave-private 64 rows, 4 chunks of 16 rows per 32-k slab
  const unsigned short* gw1 = W1te + (size_t)(wv * 64 + lr) * 1280 + ksw;
  unsigned short* lw = &Ws[(wv * 64) * 32];                    // + buf*8192 shorts
  // Wg staging (wave 0 of gate blocks): 16 rows, 1 chunk
  const unsigned short* gwg = WgTb + (size_t)lr * 1280 + ksw;
  // x f32 staging: wave-private 16 token rows, 2 chunks of 8 rows.
  // pre-swizzled source: logical 16B-block cb = (lane&7) ^ (row&7)
  const float* gxsw = xf + (size_t)(m0 + wv * 16 + (lane >> 3)) * 1280 +
                      (((lane & 7) ^ (lane >> 3)) << 2);
  char* lxB = XfB + (wv * 16) * 128;                           // + buf*8192 bytes

  // x read swizzle helpers (row r, logical cb): phys = cb ^ (r&7)
  const int cb0 = (lane >> 4) * 2;

  // ---- phase 1: h1^T tile (256 hidden x 64 tokens), K=1280, BK=32 x 40 ----
  floatx4 acc1[4][4] = {};
  floatx4 accg = {0.f, 0.f, 0.f, 0.f};

  // prologue: issue tile 0 into buf 0
  {
#pragma unroll
    for (int r = 0; r < 4; r++)
      GLDS16(gw1 + (size_t)(16 * r) * 1280, lw + r * 16 * 32);
    GLDS16(gxsw, lxB);
    GLDS16(gxsw + 8 * 1280, lxB + 1024);
    if (gate_stager) GLDS16(gwg, (char*)WgS);
  }

  for (int t = 0; t < 40; ++t) {
    asm volatile("s_waitcnt vmcnt(0)" ::: "memory");  // tile t landed (one phase of slack)
    __builtin_amdgcn_s_barrier();                     // cross-wave: x/Wg visible
    __builtin_amdgcn_sched_barrier(0);
    const int buf = t & 1;
    // issue tile t+1 into buf^1 (its readers finished before the barrier above)
    if (t < 39) {
      const int k0n = (t + 1) * 32;
      const int nb = buf ^ 1;
#pragma unroll
      for (int r = 0; r < 4; r++)
        GLDS16(gw1 + (size_t)(16 * r) * 1280 + k0n, lw + nb * 8192 + r * 16 * 32);
      GLDS16(gxsw + k0n, lxB + nb * 8192);
      GLDS16(gxsw + 8 * 1280 + k0n, lxB + nb * 8192 + 1024);
      if (gate_stager) GLDS16(gwg + k0n, (char*)WgS + nb * 1024);
    }
    __builtin_amdgcn_sched_barrier(0);
    // ds_read x (f32, swizzled) + convert to bf16 fragments
    short8 bfv[4];
#pragma unroll
    for (int j = 0; j < 4; j++) {
      const int row = j * 16 + fr;
      const char* rp = XfB + buf * 8192 + row * 128;
      float4 f0 = *(const float4*)(rp + ((cb0 ^ (fr & 7)) << 4));
      float4 f1 = *(const float4*)(rp + (((cb0 + 1) ^ (fr & 7)) << 4));
      uint4 u;
      u.x = cvtpk(f0.x, f0.y); u.y = cvtpk(f0.z, f0.w);
      u.z = cvtpk(f1.x, f1.y); u.w = cvtpk(f1.z, f1.w);
      bfv[j] = *(short8*)&u;
    }
#pragma unroll
    for (int i = 0; i < 4; i++) {
      short8 af = *(const short8*)&Ws[buf * 8192 + (wv * 64 + i * 16 + fr) * 32 + fkS];
#pragma unroll
      for (int j = 0; j < 4; j++)
        acc1[i][j] = __builtin_amdgcn_mfma_f32_16x16x32_bf16(af, bfv[j], acc1[i][j], 0, 0, 0);
    }
    if (gate_blk) {
      short8 ag = *(const short8*)&WgS[buf * 512 + fr * 32 + fkS];
      const int rg = wv * 16 + fr;
      const char* rp = XfB + buf * 8192 + rg * 128;
      float4 f0 = *(const float4*)(rp + ((cb0 ^ (rg & 7)) << 4));
      float4 f1 = *(const float4*)(rp + (((cb0 + 1) ^ (rg & 7)) << 4));
      uint4 u;
      u.x = cvtpk(f0.x, f0.y); u.y = cvtpk(f0.z, f0.w);
      u.z = cvtpk(f1.x, f1.y); u.w = cvtpk(f1.z, f1.w);
      accg = __builtin_amdgcn_mfma_f32_16x16x32_bf16(ag, *(short8*)&u, accg, 0, 0, 0);
    }
  }
  __syncthreads();  // all waves done reading Ws/Xf before h1L/W2 overwrite

  // phase-2 prologue: issue W2 tile 0 (wave-private) -- hides under epilogue
  const unsigned short* gw2 = W2te + (size_t)(wv * 32 + lr) * 256 + ksw;
  char* lw2B = (char*)smem + 32768 + (wv * 32) * 64;  // + buf*8192 bytes
  GLDS16(gw2, lw2B);
  GLDS16(gw2 + (size_t)16 * 256, lw2B + 1024);

  // ---- gate epilogue (e==0 blocks): softmax over 8 experts, write outG ----
  // accg layout: col(lane&15)=token-in-group(wv), row((lane>>4)*4+r)=expert.
  if (gate_blk) {
    const int g = lane >> 4;
    float bg0 = 0.f, bg1 = 0.f, bg2 = 0.f, bg3 = 0.f;
    if (g < 2) {
      float4 t = *(const float4*)(bg + g * 4);
      bg0 = t.x; bg1 = t.y; bg2 = t.z; bg3 = t.w;
    }
    float v0 = accg[0] + bg0, v1 = accg[1] + bg1, v2 = accg[2] + bg2, v3 = accg[3] + bg3;
    float mx = fmaxf(fmaxf(v0, v1), fmaxf(v2, v3));
    mx = fmaxf(mx, __shfl_xor(mx, 16));  // pairs g0<->g1 (g2/g3 junk stays separate)
    float e0 = __expf(v0 - mx), e1 = __expf(v1 - mx), e2 = __expf(v2 - mx), e3 = __expf(v3 - mx);
    float s = e0 + e1 + e2 + e3;
    s += __shfl_xor(s, 16);
    float inv = 1.f / s;
    if (g < 2) {
      float4 o; o.x = e0 * inv; o.y = e1 * inv; o.z = e2 * inv; o.w = e3 * inv;
      *(float4*)&outG[(size_t)(m0 + wv * 16 + fr) * 8 + g * 4] = o;
    }
  }

  // ---- epilogue 1: relu(+b1), bf16, transpose into swizzled h1L[token][k] ----
#pragma unroll
  for (int i = 0; i < 4; i++) {
    const int rowb = wv * 64 + i * 16 + rq;  // hidden k-index base (4 consecutive)
    const float4 bb = *(const float4*)(b1 + e * 256 + rowb);  // L2-hot
#pragma unroll
    for (int j = 0; j < 4; j++) {
      float v0 = acc1[i][j][0] + bb.x; v0 = v0 > 0.f ? v0 : 0.f;
      float v1 = acc1[i][j][1] + bb.y; v1 = v1 > 0.f ? v1 : 0.f;
      float v2 = acc1[i][j][2] + bb.z; v2 = v2 > 0.f ? v2 : 0.f;
      float v3 = acc1[i][j][3] + bb.w; v3 = v3 > 0.f ? v3 : 0.f;
      uint2 pk;
      pk.x = (unsigned)f2bf(v0) | ((unsigned)f2bf(v1) << 16);
      pk.y = (unsigned)f2bf(v2) | ((unsigned)f2bf(v3) << 16);
      const int row = j * 16 + fr;  // token row
      *(uint2*)((char*)h1L + ((row * 512 + rowb * 2) ^ ((row & 7) << 4))) = pk;
    }
  }
  __syncthreads();

  // ---- phase 2: h2 (128 x 64 tokens), K=256, BK=32 x 8; wave-private, 0 barriers ----
  floatx4 acc2[2][4] = {};
  for (int t = 0; t < 8; ++t) {
    asm volatile("s_waitcnt vmcnt(0)" ::: "memory");  // own W2 tile t landed
    __builtin_amdgcn_sched_barrier(0);
    const int buf = t & 1;
    if (t < 7) {
      const int k0n = (t + 1) * 32;
      GLDS16(gw2 + k0n, lw2B + (buf ^ 1) * 8192);
      GLDS16(gw2 + (size_t)16 * 256 + k0n, lw2B + (buf ^ 1) * 8192 + 1024);
    }
    __builtin_amdgcn_sched_barrier(0);
    const int k0 = t * 32;
    short8 b2v[4];
#pragma unroll
    for (int j = 0; j < 4; j++) {
      const int row = j * 16 + fr;
      b2v[j] = *(const short8*)((const char*)h1L +
               ((row * 512 + (k0 + fkL) * 2) ^ ((row & 7) << 4)));
    }
#pragma unroll
    for (int i = 0; i < 2; i++) {
      short8 a2 = *(const short8*)((const char*)smem + 32768 + buf * 8192 +
                                   (wv * 32 + i * 16 + fr) * 64 + fkS * 2);
#pragma unroll
      for (int j = 0; j < 4; j++)
        acc2[i][j] = __builtin_amdgcn_mfma_f32_16x16x32_bf16(a2, b2v[j], acc2[i][j], 0, 0, 0);
    }
  }
  __syncthreads();  // all waves done with W2 region before exS overwrite

  // ---- phase 3: expert_out = relu(h2+b2) . W3 ----
  float psum[4] = {0.f, 0.f, 0.f, 0.f};
#pragma unroll
  for (int i = 0; i < 2; i++) {
    const int rowb = wv * 32 + i * 16 + rq;  // h2 index base
    const float4 bb = *(const float4*)(b2 + e * 128 + rowb);
    const float4 ww = *(const float4*)(W3 + e * 128 + rowb);
    const float bba[4] = {bb.x, bb.y, bb.z, bb.w};
    const float wwa[4] = {ww.x, ww.y, ww.z, ww.w};
#pragma unroll
    for (int j = 0; j < 4; j++)
#pragma unroll
      for (int r = 0; r < 4; r++) {
        float v = acc2[i][j][r] + bba[r];
        v = v > 0.f ? v : 0.f;
        psum[j] += v * wwa[r];
      }
  }
#pragma unroll
  for (int j = 0; j < 4; j++) {
    float v = psum[j];
    v += __shfl_xor(v, 16);
    v += __shfl_xor(v, 32);
    psum[j] = v;
  }
  float* exS = (float*)((char*)smem + 32768);
  if (lane < 16) {
#pragma unroll
    for (int j = 0; j < 4; j++) exS[wv * 64 + j * 16 + lane] = psum[j];
  }
  __syncthreads();
  if (tid < 64) {
    float tot = exS[tid] + exS[64 + tid] + exS[128 + tid] + exS[192 + tid];
    eo[(size_t)(m0 + tid) * 8 + e] = tot + b3[e];
  }
}

// ---------------- combine: predictions = sum(gate * eo) ----------------

__global__ __launch_bounds__(256)
void combine_kernel(const float* __restrict__ outG, const float* __restrict__ eo,
                    float* __restrict__ outP) {
  int t = blockIdx.x * 256 + threadIdx.x;
  const float4* g4 = (const float4*)(outG + (size_t)t * 8);
  const float4* e4 = (const float4*)(eo + (size_t)t * 8);
  float4 ga = g4[0], gb = g4[1], ea = e4[0], eb = e4[1];
  outP[t] = ga.x * ea.x + ga.y * ea.y + ga.z * ea.z + ga.w * ea.w +
            gb.x * eb.x + gb.y * eb.y + gb.z * eb.z + gb.w * eb.w;
}

// ---------------- launch ----------------

extern "C" void kernel_launch(void* const* d_in, const int* in_sizes, int n_in,
                              void* d_out, int out_size, void* d_ws, size_t ws_size,
                              hipStream_t stream) {
  const float* x  = (const float*)d_in[0];
  const float* W1 = (const float*)d_in[1];
  const float* b1 = (const float*)d_in[2];
  const float* W2 = (const float*)d_in[3];
  const float* b2 = (const float*)d_in[4];
  const float* W3 = (const float*)d_in[5];
  const float* b3 = (const float*)d_in[6];
  const float* Wg = (const float*)d_in[7];
  const float* bg = (const float*)d_in[8];
  float* outP = (float*)d_out;   // predictions [B] f32
  float* outG = outP + NTOK;     // gate [B][8] f32

  char* ws = (char*)d_ws;
  unsigned short* W1t  = (unsigned short*)ws;               //  5,242,880
  unsigned short* W2t  = (unsigned short*)(ws + 5242880ll); //    524,288
  unsigned short* WgTb = (unsigned short*)(ws + 5767168ll); //     40,960
  float*          eo   = (float*)(ws + 5808128ll);          //  2,097,152  (tot ~7.9MB)

  pack_all_kernel<<<1488, 256, 0, stream>>>(W1, W2, Wg, W1t, W2t, WgTb);
  expert_fused_kernel<<<dim3(8, 1024), 256, 0, stream>>>(x, W1t, b1, W2t, b2, W3, b3,
                                                         WgTb, bg, outG, eo);
  combine_kernel<<<256, 256, 0, stream>>>(outG, eo, outP);
}